// Round 3
// baseline (1305.141 us; speedup 1.0000x reference)
//
#include <hip/hip_runtime.h>
#include <hip/hip_bf16.h>

#define H 128
#define W 256
#define HW (H*W)
#define NC 32
#define ND 32
#define NHID 64

// ---------------- generic 3x3 same-pad conv, tiled, 8 couts per block ----------------
__global__ void conv3x3(const float* __restrict__ in, float* __restrict__ out,
                        const float* __restrict__ w, const float* __restrict__ b,
                        int CIN, int COUT, int wstride, int dorelu) {
    __shared__ float tile[10][35];
    int tid = threadIdx.x;
    int gx0 = blockIdx.x * 32, gy0 = blockIdx.y * 8;
    int cobase = blockIdx.z * 8;
    int tx = tid & 31, ty = tid >> 5;
    float acc[8];
#pragma unroll
    for (int i = 0; i < 8; i++) acc[i] = 0.f;
    for (int c = 0; c < CIN; c++) {
        for (int i = tid; i < 340; i += 256) {
            int r = i / 34, cc = i % 34;
            int gy = gy0 + r - 1, gx = gx0 + cc - 1;
            tile[r][cc] = (gy >= 0 && gy < H && gx >= 0 && gx < W) ? in[c * HW + gy * W + gx] : 0.f;
        }
        __syncthreads();
        float v[9];
#pragma unroll
        for (int ky = 0; ky < 3; ky++)
#pragma unroll
            for (int kx = 0; kx < 3; kx++)
                v[ky * 3 + kx] = tile[ty + ky][tx + kx];
#pragma unroll
        for (int i = 0; i < 8; i++) {
            int co = cobase + i;
            if (co < COUT) {
                const float* wp = w + (size_t)co * wstride + c * 9;
#pragma unroll
                for (int k = 0; k < 9; k++) acc[i] += wp[k] * v[k];
            }
        }
        __syncthreads();
    }
    int gy = gy0 + ty, gx = gx0 + tx;
#pragma unroll
    for (int i = 0; i < 8; i++) {
        int co = cobase + i;
        if (co < COUT) {
            float r = acc[i] + b[co];
            if (dorelu) r = fmaxf(r, 0.f);
            out[co * HW + gy * W + gx] = r;
        }
    }
}

// ---------------- per-pixel channel dot for cost volume separation ----------------
__global__ void chan_dot(const float* __restrict__ lf, const float* __restrict__ rf,
                         const float* __restrict__ cvw,
                         float* __restrict__ lsum, float* __restrict__ rsum) {
    int p = blockIdx.x * 256 + threadIdx.x;
    if (p >= HW) return;
    float ls = 0.f, rs = 0.f;
    for (int c = 0; c < NC; c++) {
        ls += lf[c * HW + p] * cvw[c];
        rs += rf[c * HW + p] * cvw[NC + c];
    }
    lsum[p] = ls;
    rsum[p] = rs;
}

// ---------------- cost[d,h,w] = lsum + shift(rsum, d) + cv_b; belief init ----------------
__global__ void cost_expand(const float* __restrict__ lsum, const float* __restrict__ rsum,
                            const float* __restrict__ cvb,
                            float* __restrict__ cost, float* __restrict__ bel) {
    int idx = blockIdx.x * 256 + threadIdx.x;
    if (idx >= ND * HW) return;
    int d = idx / HW, p = idx % HW;
    int col = p & (W - 1);
    float c = lsum[p] + cvb[0];
    if (col >= d) c += rsum[p - d];
    cost[idx] = c;
    bel[idx] = c;
}

// ---------------- A[hid][p] -> At[p][hid] (LDS tile transpose) ----------------
__global__ void a_transpose(const float* __restrict__ A, float* __restrict__ At) {
    __shared__ float t[64][65];
    int p0 = blockIdx.x * 64;
    int tx = threadIdx.x & 63;
    int ty = threadIdx.x >> 6;   // 0..3
#pragma unroll
    for (int r = 0; r < 16; r++) {
        int hid = ty * 16 + r;
        t[tx][hid] = A[(size_t)hid * HW + p0 + tx];
    }
    __syncthreads();
#pragma unroll
    for (int r = 0; r < 16; r++) {
        int p = ty * 16 + r;
        At[(size_t)(p0 + p) * 64 + tx] = t[p][tx];
    }
}

// ---------------- fast MP iteration: 1 wave per block, lane = hid ----------------
// wave handles (d, 16-wide x strip, 16-row y sweep). weights in VGPRs.
// hdn row yc = y0+U computed into HARR[18] (x = x0-1 .. x0+16)
#define COMPUTE_HDN(U, HARR)                                                   \
  {                                                                            \
    const int yc_ = y0 + (U);                                                  \
    if (yc_ < 0 || yc_ >= H) {                                                 \
      _Pragma("unroll") for (int j = 0; j < 18; j++) HARR[j] = 0.f;            \
    } else {                                                                   \
      const float* Ar_ = At + (size_t)yc_ * (W * 64);                          \
      float bw_[3][3];                                                         \
      _Pragma("unroll") for (int r = 0; r < 3; r++) {                          \
        bw_[r][0] = belS[(U) + 1 + r][0];                                      \
        bw_[r][1] = belS[(U) + 1 + r][1];                                      \
      }                                                                        \
      _Pragma("unroll") for (int j = 0; j < 18; j++) {                         \
        float acc_ = Ar_[aoff[j]];                                             \
        _Pragma("unroll") for (int r = 0; r < 3; r++)                          \
          bw_[r][(j + 2) % 3] = belS[(U) + 1 + r][j + 2];                      \
        _Pragma("unroll") for (int r = 0; r < 3; r++)                          \
          _Pragma("unroll") for (int c = 0; c < 3; c++)                        \
            acc_ += w1[r * 3 + c] * bw_[r][(j + c) % 3];                       \
        HARR[j] = fmaxf(acc_, 0.f);                                            \
      }                                                                        \
      if (x0 == 0) HARR[0] = 0.f;                                              \
      if (x0 == W - 16) HARR[17] = 0.f;                                        \
    }                                                                          \
  }

__global__ __launch_bounds__(64, 4) void mp_iter_fast(
    const float* __restrict__ At,    // [HW][64]
    const float* __restrict__ cost,
    const float* __restrict__ bin,
    float* __restrict__ bout,
    const float* __restrict__ mp_w1,
    const float* __restrict__ mp_w2,
    const float* __restrict__ mp_b2) {
    __shared__ float belS[20][20];
    __shared__ float partS[16][65];

    const int lane = threadIdx.x;    // = hid
    // XCD swizzle: blocks i with same (i&7) land (heuristically) on one XCD.
    // XCD k owns y-band sy=k across all 16 x-strips and all 32 d  -> At slice ~4.7MB resides in its L2.
    const int i = blockIdx.x;
    const int xcd = i & 7;
    const int jj = i >> 3;           // 0..511
    const int sl = jj & 15;
    const int d = jj >> 4;           // 0..31
    const int strip = xcd * 16 + sl; // 0..127
    const int x0 = (strip & 15) * 16;
    const int y0 = (strip >> 4) * 16;

    // per-lane weights (hid = lane), loaded once
    float w1[9], w2[9];
#pragma unroll
    for (int k = 0; k < 9; k++) {
        w1[k] = mp_w1[lane * 297 + 288 + k];   // belief channel (index 32) of mp_w1[hid]
        w2[k] = mp_w2[lane * 9 + k];
    }
    const float b2 = mp_b2[0];

    // precomputed At column offsets (clamped), reused for all 18 rows
    int aoff[18];
#pragma unroll
    for (int j = 0; j < 18; j++) {
        int xc = x0 - 1 + j;
        xc = xc < 0 ? 0 : (xc > W - 1 ? W - 1 : xc);
        aoff[j] = xc * 64 + lane;
    }

    // stage belief tile: rows y0-2..y0+17, cols x0-2..x0+17 (zero-padded)
    const float* beld = bin + (size_t)d * HW;
#pragma unroll
    for (int it = 0; it < 7; it++) {
        int idx = it * 64 + lane;
        if (idx < 400) {
            int r = idx / 20, c = idx % 20;
            int gy = y0 - 2 + r, gx = x0 - 2 + c;
            belS[r][c] = (gy >= 0 && gy < H && gx >= 0 && gx < W) ? beld[gy * W + gx] : 0.f;
        }
    }
    __syncthreads();   // single-wave workgroup: compiles to a cheap wave-local fence

    float h2[18], h1[18], h0[18];
    COMPUTE_HDN(-1, h2);
    COMPUTE_HDN(0, h1);

    for (int t = 0; t < 16; t++) {
        COMPUTE_HDN(t + 1, h0);
        // msg partials: lane's hid contribution to each of 16 output pixels
#pragma unroll
        for (int jo = 0; jo < 16; jo++) {
            float p = w2[0] * h2[jo] + w2[1] * h2[jo + 1] + w2[2] * h2[jo + 2]
                    + w2[3] * h1[jo] + w2[4] * h1[jo + 1] + w2[5] * h1[jo + 2]
                    + w2[6] * h0[jo] + w2[7] * h0[jo + 1] + w2[8] * h0[jo + 2];
            partS[jo][lane] = p;
        }
        __syncthreads();
        // transpose-reduce 64 lanes -> 16 pixels
        {
            int p = lane & 15, q = lane >> 4;
            float s = 0.f;
#pragma unroll
            for (int j = 0; j < 16; j++) s += partS[p][q * 16 + j];
            s += __shfl_xor(s, 16);
            s += __shfl_xor(s, 32);
            if (q == 0) {
                size_t o = (size_t)d * HW + (size_t)(y0 + t) * W + x0 + p;
                bout[o] = cost[o] + s + b2;
            }
        }
        __syncthreads();
        // shift history down one row
#pragma unroll
        for (int j = 0; j < 18; j++) { h2[j] = h1[j]; h1[j] = h0[j]; }
    }
}

// ---------------- softmax over D of -belief, expectation of d ----------------
__global__ void softmax_disp(const float* __restrict__ bel, float* __restrict__ disp) {
    int p = blockIdx.x * 256 + threadIdx.x;
    if (p >= HW) return;
    float v[ND];
    float m = -1e30f;
#pragma unroll
    for (int d = 0; d < ND; d++) {
        v[d] = -bel[d * HW + p];
        m = fmaxf(m, v[d]);
    }
    float s = 0.f, ws = 0.f;
#pragma unroll
    for (int d = 0; d < ND; d++) {
        float e = __expf(v[d] - m);
        s += e;
        ws += e * (float)d;
    }
    disp[p] = ws / s;
}

// ---------------- concat left_img(3ch) + disparity -> 4ch ----------------
__global__ void concat4(const float* __restrict__ left, const float* __restrict__ disp,
                        float* __restrict__ x4) {
    int idx = blockIdx.x * 256 + threadIdx.x;
    if (idx >= 4 * HW) return;
    int c = idx / HW, p = idx % HW;
    x4[idx] = (c < 3) ? left[idx] : disp[p];
}

// ---------------- out = disp + res ----------------
__global__ void final_add(const float* __restrict__ disp, const float* __restrict__ res,
                          float* __restrict__ out) {
    int p = blockIdx.x * 256 + threadIdx.x;
    if (p >= HW) return;
    out[p] = disp[p] + res[p];
}

extern "C" void kernel_launch(void* const* d_in, const int* in_sizes, int n_in,
                              void* d_out, int out_size, void* d_ws, size_t ws_size,
                              hipStream_t stream) {
    const float* left   = (const float*)d_in[0];
    const float* right  = (const float*)d_in[1];
    const float* fe_w1  = (const float*)d_in[2];
    const float* fe_b1  = (const float*)d_in[3];
    const float* fe_w2  = (const float*)d_in[4];
    const float* fe_b2  = (const float*)d_in[5];
    const float* cv_w   = (const float*)d_in[6];
    const float* cv_b   = (const float*)d_in[7];
    const float* mp_w1  = (const float*)d_in[8];
    const float* mp_b1  = (const float*)d_in[9];
    const float* mp_w2  = (const float*)d_in[10];
    const float* mp_b2  = (const float*)d_in[11];
    const float* rf_w1  = (const float*)d_in[12];
    const float* rf_b1  = (const float*)d_in[13];
    const float* rf_w2  = (const float*)d_in[14];
    const float* rf_b2  = (const float*)d_in[15];
    const float* rf_w3  = (const float*)d_in[16];
    const float* rf_b3  = (const float*)d_in[17];
    float* out = (float*)d_out;

    float* ws = (float*)d_ws;
    // layout (floats):
    float* At    = ws;                  // 2M floats [HW][64]; also fe tmp (1M) earlier, r1 (1M) later
    float* tmp   = ws;                  // fe intermediate (1M), before At exists
    float* lf    = ws + 2097152;        // 32*HW
    float* rfeat = ws + 3145728;        // 32*HW (r2 aliases later)
    float* cost  = ws + 4194304;        // 32*HW  (raw A lower half before cost_expand)
    float* Araw  = ws + 4194304;        // 2M floats transient (= cost+bel regions)
    float* bel   = ws + 5242880;        // 32*HW
    float* bel2  = ws + 6291456;        // 32*HW
    float* lsum  = ws + 7340032;        // HW
    float* rsum  = ws + 7372800;        // HW
    float* disp  = ws + 7405568;        // HW
    float* x4    = ws + 7438336;        // 4*HW
    float* res   = ws + 7569408;        // HW

    dim3 blk(256);
    dim3 gconv(8, 16, 4);   // COUT=32
    dim3 gconv64(8, 16, 8); // COUT=64
    dim3 gconv1(8, 16, 1);  // COUT=1

    // feature extraction
    conv3x3<<<gconv, blk, 0, stream>>>(left, tmp, fe_w1, fe_b1, 3, 32, 27, 1);
    conv3x3<<<gconv, blk, 0, stream>>>(tmp, lf, fe_w2, fe_b2, 32, 32, 288, 1);
    conv3x3<<<gconv, blk, 0, stream>>>(right, tmp, fe_w1, fe_b1, 3, 32, 27, 1);
    conv3x3<<<gconv, blk, 0, stream>>>(tmp, rfeat, fe_w2, fe_b2, 32, 32, 288, 1);

    // cost volume (separated)
    chan_dot<<<dim3(HW / 256), blk, 0, stream>>>(lf, rfeat, cv_w, lsum, rsum);

    // hoisted lf-part of mp conv1 (includes mp_b1, no relu) -> Araw, then transpose -> At
    conv3x3<<<gconv64, blk, 0, stream>>>(lf, Araw, mp_w1, mp_b1, 32, 64, 297, 0);
    a_transpose<<<dim3(HW / 64), blk, 0, stream>>>(Araw, At);

    // cost + belief init (overwrites Araw region, after transpose in stream order)
    cost_expand<<<dim3(ND * HW / 256), blk, 0, stream>>>(lsum, rsum, cv_b, cost, bel);

    // 5 MP iterations, ping-pong — 1 wave per block, 4096 blocks
    dim3 gmp(4096);
    dim3 wblk(64);
    mp_iter_fast<<<gmp, wblk, 0, stream>>>(At, cost, bel,  bel2, mp_w1, mp_w2, mp_b2);
    mp_iter_fast<<<gmp, wblk, 0, stream>>>(At, cost, bel2, bel,  mp_w1, mp_w2, mp_b2);
    mp_iter_fast<<<gmp, wblk, 0, stream>>>(At, cost, bel,  bel2, mp_w1, mp_w2, mp_b2);
    mp_iter_fast<<<gmp, wblk, 0, stream>>>(At, cost, bel2, bel,  mp_w1, mp_w2, mp_b2);
    mp_iter_fast<<<gmp, wblk, 0, stream>>>(At, cost, bel,  bel2, mp_w1, mp_w2, mp_b2);

    softmax_disp<<<dim3(HW / 256), blk, 0, stream>>>(bel2, disp);

    // refinement (At dead now; reuse ws+0 for r1)
    concat4<<<dim3(4 * HW / 256), blk, 0, stream>>>(left, disp, x4);
    conv3x3<<<gconv, blk, 0, stream>>>(x4, At, rf_w1, rf_b1, 4, 32, 36, 1);
    conv3x3<<<gconv, blk, 0, stream>>>(At, rfeat, rf_w2, rf_b2, 32, 32, 288, 1);
    conv3x3<<<gconv1, blk, 0, stream>>>(rfeat, res, rf_w3, rf_b3, 32, 1, 288, 0);

    final_add<<<dim3(HW / 256), blk, 0, stream>>>(disp, res, out);
}

// Round 4
// 752.934 us; speedup vs baseline: 1.7334x; 1.7334x over previous
//
#include <hip/hip_runtime.h>
#include <hip/hip_bf16.h>

#define H 128
#define W 256
#define HW (H*W)
#define NC 32
#define ND 32
#define NHID 64

// ---------------- generic 3x3 same-pad conv, tiled, 8 couts per block ----------------
__global__ void conv3x3(const float* __restrict__ in, float* __restrict__ out,
                        const float* __restrict__ w, const float* __restrict__ b,
                        int CIN, int COUT, int wstride, int dorelu) {
    __shared__ float tile[10][35];
    int tid = threadIdx.x;
    int gx0 = blockIdx.x * 32, gy0 = blockIdx.y * 8;
    int cobase = blockIdx.z * 8;
    int tx = tid & 31, ty = tid >> 5;
    float acc[8];
#pragma unroll
    for (int i = 0; i < 8; i++) acc[i] = 0.f;
    for (int c = 0; c < CIN; c++) {
        for (int i = tid; i < 340; i += 256) {
            int r = i / 34, cc = i % 34;
            int gy = gy0 + r - 1, gx = gx0 + cc - 1;
            tile[r][cc] = (gy >= 0 && gy < H && gx >= 0 && gx < W) ? in[c * HW + gy * W + gx] : 0.f;
        }
        __syncthreads();
        float v[9];
#pragma unroll
        for (int ky = 0; ky < 3; ky++)
#pragma unroll
            for (int kx = 0; kx < 3; kx++)
                v[ky * 3 + kx] = tile[ty + ky][tx + kx];
#pragma unroll
        for (int i = 0; i < 8; i++) {
            int co = cobase + i;
            if (co < COUT) {
                const float* wp = w + (size_t)co * wstride + c * 9;
#pragma unroll
                for (int k = 0; k < 9; k++) acc[i] += wp[k] * v[k];
            }
        }
        __syncthreads();
    }
    int gy = gy0 + ty, gx = gx0 + tx;
#pragma unroll
    for (int i = 0; i < 8; i++) {
        int co = cobase + i;
        if (co < COUT) {
            float r = acc[i] + b[co];
            if (dorelu) r = fmaxf(r, 0.f);
            out[co * HW + gy * W + gx] = r;
        }
    }
}

// ---------------- per-pixel channel dot for cost volume separation ----------------
__global__ void chan_dot(const float* __restrict__ lf, const float* __restrict__ rf,
                         const float* __restrict__ cvw,
                         float* __restrict__ lsum, float* __restrict__ rsum) {
    int p = blockIdx.x * 256 + threadIdx.x;
    if (p >= HW) return;
    float ls = 0.f, rs = 0.f;
    for (int c = 0; c < NC; c++) {
        ls += lf[c * HW + p] * cvw[c];
        rs += rf[c * HW + p] * cvw[NC + c];
    }
    lsum[p] = ls;
    rsum[p] = rs;
}

// ---------------- cost[d,h,w] = lsum + shift(rsum, d) + cv_b; belief init ----------------
__global__ void cost_expand(const float* __restrict__ lsum, const float* __restrict__ rsum,
                            const float* __restrict__ cvb,
                            float* __restrict__ cost, float* __restrict__ bel) {
    int idx = blockIdx.x * 256 + threadIdx.x;
    if (idx >= ND * HW) return;
    int d = idx / HW, p = idx % HW;
    int col = p & (W - 1);
    float c = lsum[p] + cvb[0];
    if (col >= d) c += rsum[p - d];
    cost[idx] = c;
    bel[idx] = c;
}

// ---------------- A[hid][p] -> At[p][hid] (LDS tile transpose) ----------------
__global__ void a_transpose(const float* __restrict__ A, float* __restrict__ At) {
    __shared__ float t[64][65];
    int p0 = blockIdx.x * 64;
    int tx = threadIdx.x & 63;
    int ty = threadIdx.x >> 6;   // 0..3
#pragma unroll
    for (int r = 0; r < 16; r++) {
        int hid = ty * 16 + r;
        t[tx][hid] = A[(size_t)hid * HW + p0 + tx];
    }
    __syncthreads();
#pragma unroll
    for (int r = 0; r < 16; r++) {
        int p = ty * 16 + r;
        At[(size_t)(p0 + p) * 64 + tx] = t[p][tx];
    }
}

// ---------------- fast MP iteration: 1 wave per block, lane = hid ----------------
// wave handles (d, 16-wide x strip, 16-row y sweep). weights in VGPRs.
// hdn row yc = y0+U computed into HARR[18] (x = x0-1 .. x0+16)
#define COMPUTE_HDN(U, HARR)                                                   \
  {                                                                            \
    const int yc_ = y0 + (U);                                                  \
    if (yc_ < 0 || yc_ >= H) {                                                 \
      _Pragma("unroll") for (int j = 0; j < 18; j++) HARR[j] = 0.f;            \
    } else {                                                                   \
      const float* Ar_ = At + (size_t)yc_ * (W * 64);                          \
      float bw_[3][3];                                                         \
      _Pragma("unroll") for (int r = 0; r < 3; r++) {                          \
        bw_[r][0] = belS[(U) + 1 + r][0];                                      \
        bw_[r][1] = belS[(U) + 1 + r][1];                                      \
      }                                                                        \
      _Pragma("unroll") for (int j = 0; j < 18; j++) {                         \
        float acc_ = Ar_[aoff[j]];                                             \
        _Pragma("unroll") for (int r = 0; r < 3; r++)                          \
          bw_[r][(j + 2) % 3] = belS[(U) + 1 + r][j + 2];                      \
        _Pragma("unroll") for (int r = 0; r < 3; r++)                          \
          _Pragma("unroll") for (int c = 0; c < 3; c++)                        \
            acc_ += w1[r * 3 + c] * bw_[r][(j + c) % 3];                       \
        HARR[j] = fmaxf(acc_, 0.f);                                            \
      }                                                                        \
      if (x0 == 0) HARR[0] = 0.f;                                              \
      if (x0 == W - 16) HARR[17] = 0.f;                                        \
    }                                                                          \
  }

// NOTE: launch_bounds min-waves=1 — R3's (64,4) forced VGPR=64 and spilled the
// rolling hdn arrays to scratch (WRITE_SIZE 315MB/dispatch). Cap 512, let the
// allocator take the ~100 it needs.
__global__ __launch_bounds__(64, 1) void mp_iter_fast(
    const float* __restrict__ At,    // [HW][64]
    const float* __restrict__ cost,
    const float* __restrict__ bin,
    float* __restrict__ bout,
    const float* __restrict__ mp_w1,
    const float* __restrict__ mp_w2,
    const float* __restrict__ mp_b2) {
    __shared__ float belS[20][20];
    __shared__ float partS[16][65];

    const int lane = threadIdx.x;    // = hid
    // XCD swizzle: blocks i with same (i&7) land (round-robin) on one XCD.
    // XCD k owns y-band k across all 16 x-strips and all 32 d -> At band ~1.2MB + bel/cost ~1.2MB in its L2.
    const int i = blockIdx.x;
    const int xcd = i & 7;
    const int jj = i >> 3;           // 0..511
    const int sl = jj & 15;
    const int d = jj >> 4;           // 0..31
    const int strip = xcd * 16 + sl; // 0..127
    const int x0 = (strip & 15) * 16;
    const int y0 = (strip >> 4) * 16;

    // per-lane weights (hid = lane), loaded once
    float w1[9], w2[9];
#pragma unroll
    for (int k = 0; k < 9; k++) {
        w1[k] = mp_w1[lane * 297 + 288 + k];   // belief channel (index 32) of mp_w1[hid]
        w2[k] = mp_w2[lane * 9 + k];
    }
    const float b2 = mp_b2[0];

    // precomputed At column offsets (clamped), reused for all 18 rows
    int aoff[18];
#pragma unroll
    for (int j = 0; j < 18; j++) {
        int xc = x0 - 1 + j;
        xc = xc < 0 ? 0 : (xc > W - 1 ? W - 1 : xc);
        aoff[j] = xc * 64 + lane;
    }

    // stage belief tile: rows y0-2..y0+17, cols x0-2..x0+17 (zero-padded)
    const float* beld = bin + (size_t)d * HW;
#pragma unroll
    for (int it = 0; it < 7; it++) {
        int idx = it * 64 + lane;
        if (idx < 400) {
            int r = idx / 20, c = idx % 20;
            int gy = y0 - 2 + r, gx = x0 - 2 + c;
            belS[r][c] = (gy >= 0 && gy < H && gx >= 0 && gx < W) ? beld[gy * W + gx] : 0.f;
        }
    }
    __syncthreads();   // single-wave workgroup: cheap

    float h2[18], h1[18], h0[18];
    COMPUTE_HDN(-1, h2);
    COMPUTE_HDN(0, h1);

    for (int t = 0; t < 16; t++) {
        COMPUTE_HDN(t + 1, h0);
        // msg partials: lane's hid contribution to each of 16 output pixels
#pragma unroll
        for (int jo = 0; jo < 16; jo++) {
            float p = w2[0] * h2[jo] + w2[1] * h2[jo + 1] + w2[2] * h2[jo + 2]
                    + w2[3] * h1[jo] + w2[4] * h1[jo + 1] + w2[5] * h1[jo + 2]
                    + w2[6] * h0[jo] + w2[7] * h0[jo + 1] + w2[8] * h0[jo + 2];
            partS[jo][lane] = p;
        }
        __syncthreads();
        // transpose-reduce 64 lanes -> 16 pixels
        {
            int p = lane & 15, q = lane >> 4;
            float s = 0.f;
#pragma unroll
            for (int j = 0; j < 16; j++) s += partS[p][q * 16 + j];
            s += __shfl_xor(s, 16);
            s += __shfl_xor(s, 32);
            if (q == 0) {
                size_t o = (size_t)d * HW + (size_t)(y0 + t) * W + x0 + p;
                bout[o] = cost[o] + s + b2;
            }
        }
        __syncthreads();
        // shift history down one row
#pragma unroll
        for (int j = 0; j < 18; j++) { h2[j] = h1[j]; h1[j] = h0[j]; }
    }
}

// ---------------- softmax over D of -belief, expectation of d ----------------
__global__ void softmax_disp(const float* __restrict__ bel, float* __restrict__ disp) {
    int p = blockIdx.x * 256 + threadIdx.x;
    if (p >= HW) return;
    float v[ND];
    float m = -1e30f;
#pragma unroll
    for (int d = 0; d < ND; d++) {
        v[d] = -bel[d * HW + p];
        m = fmaxf(m, v[d]);
    }
    float s = 0.f, ws = 0.f;
#pragma unroll
    for (int d = 0; d < ND; d++) {
        float e = __expf(v[d] - m);
        s += e;
        ws += e * (float)d;
    }
    disp[p] = ws / s;
}

// ---------------- concat left_img(3ch) + disparity -> 4ch ----------------
__global__ void concat4(const float* __restrict__ left, const float* __restrict__ disp,
                        float* __restrict__ x4) {
    int idx = blockIdx.x * 256 + threadIdx.x;
    if (idx >= 4 * HW) return;
    int c = idx / HW, p = idx % HW;
    x4[idx] = (c < 3) ? left[idx] : disp[p];
}

// ---------------- out = disp + res ----------------
__global__ void final_add(const float* __restrict__ disp, const float* __restrict__ res,
                          float* __restrict__ out) {
    int p = blockIdx.x * 256 + threadIdx.x;
    if (p >= HW) return;
    out[p] = disp[p] + res[p];
}

extern "C" void kernel_launch(void* const* d_in, const int* in_sizes, int n_in,
                              void* d_out, int out_size, void* d_ws, size_t ws_size,
                              hipStream_t stream) {
    const float* left   = (const float*)d_in[0];
    const float* right  = (const float*)d_in[1];
    const float* fe_w1  = (const float*)d_in[2];
    const float* fe_b1  = (const float*)d_in[3];
    const float* fe_w2  = (const float*)d_in[4];
    const float* fe_b2  = (const float*)d_in[5];
    const float* cv_w   = (const float*)d_in[6];
    const float* cv_b   = (const float*)d_in[7];
    const float* mp_w1  = (const float*)d_in[8];
    const float* mp_b1  = (const float*)d_in[9];
    const float* mp_w2  = (const float*)d_in[10];
    const float* mp_b2  = (const float*)d_in[11];
    const float* rf_w1  = (const float*)d_in[12];
    const float* rf_b1  = (const float*)d_in[13];
    const float* rf_w2  = (const float*)d_in[14];
    const float* rf_b2  = (const float*)d_in[15];
    const float* rf_w3  = (const float*)d_in[16];
    const float* rf_b3  = (const float*)d_in[17];
    float* out = (float*)d_out;

    float* ws = (float*)d_ws;
    // layout (floats):
    float* At    = ws;                  // 2M floats [HW][64]; also fe tmp (1M) earlier, r1 (1M) later
    float* tmp   = ws;                  // fe intermediate (1M), before At exists
    float* lf    = ws + 2097152;        // 32*HW
    float* rfeat = ws + 3145728;        // 32*HW (r2 aliases later)
    float* cost  = ws + 4194304;        // 32*HW  (raw A lower half before cost_expand)
    float* Araw  = ws + 4194304;        // 2M floats transient (= cost+bel regions)
    float* bel   = ws + 5242880;        // 32*HW
    float* bel2  = ws + 6291456;        // 32*HW
    float* lsum  = ws + 7340032;        // HW
    float* rsum  = ws + 7372800;        // HW
    float* disp  = ws + 7405568;        // HW
    float* x4    = ws + 7438336;        // 4*HW
    float* res   = ws + 7569408;        // HW

    dim3 blk(256);
    dim3 gconv(8, 16, 4);   // COUT=32
    dim3 gconv64(8, 16, 8); // COUT=64
    dim3 gconv1(8, 16, 1);  // COUT=1

    // feature extraction
    conv3x3<<<gconv, blk, 0, stream>>>(left, tmp, fe_w1, fe_b1, 3, 32, 27, 1);
    conv3x3<<<gconv, blk, 0, stream>>>(tmp, lf, fe_w2, fe_b2, 32, 32, 288, 1);
    conv3x3<<<gconv, blk, 0, stream>>>(right, tmp, fe_w1, fe_b1, 3, 32, 27, 1);
    conv3x3<<<gconv, blk, 0, stream>>>(tmp, rfeat, fe_w2, fe_b2, 32, 32, 288, 1);

    // cost volume (separated)
    chan_dot<<<dim3(HW / 256), blk, 0, stream>>>(lf, rfeat, cv_w, lsum, rsum);

    // hoisted lf-part of mp conv1 (includes mp_b1, no relu) -> Araw, then transpose -> At
    conv3x3<<<gconv64, blk, 0, stream>>>(lf, Araw, mp_w1, mp_b1, 32, 64, 297, 0);
    a_transpose<<<dim3(HW / 64), blk, 0, stream>>>(Araw, At);

    // cost + belief init (overwrites Araw region, after transpose in stream order)
    cost_expand<<<dim3(ND * HW / 256), blk, 0, stream>>>(lsum, rsum, cv_b, cost, bel);

    // 5 MP iterations, ping-pong — 1 wave per block, 4096 blocks
    dim3 gmp(4096);
    dim3 wblk(64);
    mp_iter_fast<<<gmp, wblk, 0, stream>>>(At, cost, bel,  bel2, mp_w1, mp_w2, mp_b2);
    mp_iter_fast<<<gmp, wblk, 0, stream>>>(At, cost, bel2, bel,  mp_w1, mp_w2, mp_b2);
    mp_iter_fast<<<gmp, wblk, 0, stream>>>(At, cost, bel,  bel2, mp_w1, mp_w2, mp_b2);
    mp_iter_fast<<<gmp, wblk, 0, stream>>>(At, cost, bel2, bel,  mp_w1, mp_w2, mp_b2);
    mp_iter_fast<<<gmp, wblk, 0, stream>>>(At, cost, bel,  bel2, mp_w1, mp_w2, mp_b2);

    softmax_disp<<<dim3(HW / 256), blk, 0, stream>>>(bel2, disp);

    // refinement (At dead now; reuse ws+0 for r1)
    concat4<<<dim3(4 * HW / 256), blk, 0, stream>>>(left, disp, x4);
    conv3x3<<<gconv, blk, 0, stream>>>(x4, At, rf_w1, rf_b1, 4, 32, 36, 1);
    conv3x3<<<gconv, blk, 0, stream>>>(At, rfeat, rf_w2, rf_b2, 32, 32, 288, 1);
    conv3x3<<<gconv1, blk, 0, stream>>>(rfeat, res, rf_w3, rf_b3, 32, 1, 288, 0);

    final_add<<<dim3(HW / 256), blk, 0, stream>>>(disp, res, out);
}

// Round 5
// 691.741 us; speedup vs baseline: 1.8867x; 1.0885x over previous
//
#include <hip/hip_runtime.h>
#include <hip/hip_bf16.h>

#define H 128
#define W 256
#define HW (H*W)
#define NC 32
#define ND 32
#define NHID 64

// ---------------- generic 3x3 same-pad conv, tiled, 8 couts, 4 cin per stage ----------------
__global__ void conv3x3(const float* __restrict__ in, float* __restrict__ out,
                        const float* __restrict__ w, const float* __restrict__ b,
                        int CIN, int COUT, int wstride, int dorelu,
                        const float* __restrict__ addin) {
    __shared__ float tile[4][10][35];
    int tid = threadIdx.x;
    int gx0 = blockIdx.x * 32, gy0 = blockIdx.y * 8;
    int cobase = blockIdx.z * 8;
    int tx = tid & 31, ty = tid >> 5;
    float acc[8];
#pragma unroll
    for (int i = 0; i < 8; i++) acc[i] = 0.f;
    for (int c0 = 0; c0 < CIN; c0 += 4) {
        int nch = CIN - c0; if (nch > 4) nch = 4;
        for (int i = tid; i < nch * 340; i += 256) {
            int ch = i / 340, rem = i % 340;
            int r = rem / 34, cc = rem % 34;
            int gy = gy0 + r - 1, gx = gx0 + cc - 1;
            tile[ch][r][cc] = (gy >= 0 && gy < H && gx >= 0 && gx < W)
                              ? in[(size_t)(c0 + ch) * HW + gy * W + gx] : 0.f;
        }
        __syncthreads();
        for (int ch = 0; ch < nch; ch++) {
            float v[9];
#pragma unroll
            for (int ky = 0; ky < 3; ky++)
#pragma unroll
                for (int kx = 0; kx < 3; kx++)
                    v[ky * 3 + kx] = tile[ch][ty + ky][tx + kx];
#pragma unroll
            for (int i = 0; i < 8; i++) {
                int co = cobase + i;
                if (co < COUT) {
                    const float* wp = w + (size_t)co * wstride + (size_t)(c0 + ch) * 9;
#pragma unroll
                    for (int k = 0; k < 9; k++) acc[i] += wp[k] * v[k];
                }
            }
        }
        __syncthreads();
    }
    int gy = gy0 + ty, gx = gx0 + tx;
    float ad = addin ? addin[gy * W + gx] : 0.f;
#pragma unroll
    for (int i = 0; i < 8; i++) {
        int co = cobase + i;
        if (co < COUT) {
            float r = acc[i] + b[co];
            if (dorelu) r = fmaxf(r, 0.f);
            r += ad;
            out[co * HW + gy * W + gx] = r;
        }
    }
}

// ---------------- per-pixel channel dot for cost volume separation ----------------
__global__ void chan_dot(const float* __restrict__ lf, const float* __restrict__ rf,
                         const float* __restrict__ cvw,
                         float* __restrict__ lsum, float* __restrict__ rsum) {
    int p = blockIdx.x * 256 + threadIdx.x;
    if (p >= HW) return;
    float ls = 0.f, rs = 0.f;
    for (int c = 0; c < NC; c++) {
        ls += lf[c * HW + p] * cvw[c];
        rs += rf[c * HW + p] * cvw[NC + c];
    }
    lsum[p] = ls;
    rsum[p] = rs;
}

// ---------------- cost[d,h,w] = lsum + shift(rsum, d) + cv_b; belief init ----------------
__global__ void cost_expand(const float* __restrict__ lsum, const float* __restrict__ rsum,
                            const float* __restrict__ cvb,
                            float* __restrict__ cost, float* __restrict__ bel) {
    int idx = blockIdx.x * 256 + threadIdx.x;
    if (idx >= ND * HW) return;
    int d = idx / HW, p = idx % HW;
    int col = p & (W - 1);
    float c = lsum[p] + cvb[0];
    if (col >= d) c += rsum[p - d];
    cost[idx] = c;
    bel[idx] = c;
}

// ---------------- A[hid][p] -> At[p][hid] (LDS tile transpose) ----------------
__global__ void a_transpose(const float* __restrict__ A, float* __restrict__ At) {
    __shared__ float t[64][65];
    int p0 = blockIdx.x * 64;
    int tx = threadIdx.x & 63;
    int ty = threadIdx.x >> 6;   // 0..3
#pragma unroll
    for (int r = 0; r < 16; r++) {
        int hid = ty * 16 + r;
        t[tx][hid] = A[(size_t)hid * HW + p0 + tx];
    }
    __syncthreads();
#pragma unroll
    for (int r = 0; r < 16; r++) {
        int p = ty * 16 + r;
        At[(size_t)(p0 + p) * 64 + tx] = t[p][tx];
    }
}

// ---------------- fast MP iteration v3: pipelined At rows, no in-loop barriers ----------------
// wave = (d, 16-wide x strip, 16-row y sweep), lane = hid.
// LOADROW: issue 18 global loads for hdn row yc (one base ptr + imm offsets); bump ptr.
#define LOADROW(YC, AR)                                                        \
  {                                                                            \
    if ((YC) >= 0 && (YC) < H) {                                               \
      AR[0] = bp[e0off];                                                       \
      _Pragma("unroll") for (int j = 1; j < 17; j++) AR[j] = bp[(j - 8) * 64]; \
      AR[17] = bp[e17off];                                                     \
    }                                                                          \
    bp += W * 64;                                                              \
  }

// COMPUTE: hdn row yc = y0+U from preloaded AR + belS window (FMA only)
#define COMPUTE(U, AR, HARR)                                                   \
  {                                                                            \
    const int yc_ = y0 + (U);                                                  \
    if (yc_ < 0 || yc_ >= H) {                                                 \
      _Pragma("unroll") for (int j = 0; j < 18; j++) HARR[j] = 0.f;            \
    } else {                                                                   \
      float bw_[3][3];                                                         \
      _Pragma("unroll") for (int r = 0; r < 3; r++) {                          \
        bw_[r][0] = belS[(U) + 1 + r][0];                                      \
        bw_[r][1] = belS[(U) + 1 + r][1];                                      \
      }                                                                        \
      _Pragma("unroll") for (int j = 0; j < 18; j++) {                         \
        float acc_ = AR[j];                                                    \
        _Pragma("unroll") for (int r = 0; r < 3; r++)                          \
          bw_[r][(j + 2) % 3] = belS[(U) + 1 + r][j + 2];                      \
        _Pragma("unroll") for (int r = 0; r < 3; r++)                          \
          _Pragma("unroll") for (int c = 0; c < 3; c++)                        \
            acc_ += w1[r * 3 + c] * bw_[r][(j + c) % 3];                       \
        HARR[j] = fmaxf(acc_, 0.f);                                            \
      }                                                                        \
      if (x0 == 0) HARR[0] = 0.f;                                              \
      if (x0 == W - 16) HARR[17] = 0.f;                                        \
    }                                                                          \
  }

// EMIT: conv2 partials -> LDS transpose-reduce -> belief write for output row t
#define EMIT(T)                                                                \
  {                                                                            \
    _Pragma("unroll") for (int jo = 0; jo < 16; jo++) {                        \
      float pp = w2[0] * h2[jo] + w2[1] * h2[jo + 1] + w2[2] * h2[jo + 2]      \
               + w2[3] * h1[jo] + w2[4] * h1[jo + 1] + w2[5] * h1[jo + 2]      \
               + w2[6] * h0[jo] + w2[7] * h0[jo + 1] + w2[8] * h0[jo + 2];     \
      partS[jo][lane] = pp;                                                    \
    }                                                                          \
    asm volatile("s_waitcnt lgkmcnt(0)" ::: "memory");                         \
    {                                                                          \
      const float4* pr = (const float4*)&partS[pq][qq * 16];                   \
      float4 v0 = pr[0], v1 = pr[1], v2 = pr[2], v3 = pr[3];                   \
      float s_ = (((v0.x + v0.y) + (v0.z + v0.w)) +                            \
                  ((v1.x + v1.y) + (v1.z + v1.w))) +                           \
                 (((v2.x + v2.y) + (v2.z + v2.w)) +                            \
                  ((v3.x + v3.y) + (v3.z + v3.w)));                            \
      s_ += __shfl_xor(s_, 16);                                                \
      s_ += __shfl_xor(s_, 32);                                                \
      if (qq == 0)                                                             \
        bout[obase + (size_t)(T) * W] = costS[(T)][pq] + s_ + b2;              \
      asm volatile("s_waitcnt lgkmcnt(0)" ::: "memory");                       \
    }                                                                          \
  }

#define SHIFTH                                                                 \
  { _Pragma("unroll") for (int j = 0; j < 18; j++) { h2[j] = h1[j]; h1[j] = h0[j]; } }

__global__ __launch_bounds__(64, 1) void mp_iter_fast(
    const float* __restrict__ At,    // [HW][64]
    const float* __restrict__ cost,
    const float* __restrict__ bin,
    float* __restrict__ bout,
    const float* __restrict__ mp_w1,
    const float* __restrict__ mp_w2,
    const float* __restrict__ mp_b2) {
    __shared__ float belS[20][20];
    __shared__ float costS[16][16];
    __shared__ float partS[16][68];   // 68: float4-aligned rows, conflict-benign

    const int lane = threadIdx.x;    // = hid
    // XCD swizzle: XCD k owns y-band k across all strips/d -> At band + bel/cost band L2-resident
    const int i = blockIdx.x;
    const int xcd = i & 7;
    const int jj = i >> 3;           // 0..511
    const int sl = jj & 15;
    const int d = jj >> 4;           // 0..31
    const int strip = xcd * 16 + sl; // 0..127
    const int x0 = (strip & 15) * 16;
    const int y0 = (strip >> 4) * 16;

    // per-lane weights (hid = lane), loaded once
    float w1[9], w2[9];
#pragma unroll
    for (int k = 0; k < 9; k++) {
        w1[k] = mp_w1[lane * 297 + 288 + k];   // belief channel (index 32)
        w2[k] = mp_w2[lane * 9 + k];
    }
    const float b2 = mp_b2[0];

    // At running pointer: row y0-1, centered at column x0+7 (imm offsets cover x0-1..x0+16)
    const float* bp = At + (size_t)(y0 - 1) * (W * 64) + (x0 + 7) * 64 + lane;
    const int e0off  = (x0 == 0)      ? -448 : -512;  // clamp(x0-1,0) relative to center
    const int e17off = (x0 == W - 16) ?  512 :  576;  // clamp(x0+16,W-1) relative to center

    // stage belief tile (rows y0-2..y0+17, cols x0-2..x0+17, zero-padded) + cost tile
    const float* beld = bin + (size_t)d * HW;
#pragma unroll
    for (int it = 0; it < 7; it++) {
        int idx = it * 64 + lane;
        if (idx < 400) {
            int r = idx / 20, c = idx % 20;
            int gy = y0 - 2 + r, gx = x0 - 2 + c;
            belS[r][c] = (gy >= 0 && gy < H && gx >= 0 && gx < W) ? beld[gy * W + gx] : 0.f;
        }
    }
#pragma unroll
    for (int it = 0; it < 4; it++) {
        int idx = it * 64 + lane;
        int r = idx >> 4, c = idx & 15;
        costS[r][c] = cost[(size_t)d * HW + (size_t)(y0 + r) * W + x0 + c];
    }
    __syncthreads();

    const int pq = lane & 15, qq = lane >> 4;
    const size_t obase = (size_t)d * HW + (size_t)y0 * W + x0 + pq;

    float aA[18], aB[18];
    float h2[18], h1[18], h0[18];

    // software pipeline: load row k+1 while computing row k
    LOADROW(y0 - 1, aA);
    LOADROW(y0, aB);
    COMPUTE(-1, aA, h2);
    LOADROW(y0 + 1, aA);
    COMPUTE(0, aB, h1);

    for (int tt = 0; tt < 8; tt++) {
        const int t0 = tt * 2;
        LOADROW(y0 + t0 + 2, aB);
        COMPUTE(t0 + 1, aA, h0);
        EMIT(t0);
        SHIFTH;
        if (tt < 7) { LOADROW(y0 + t0 + 3, aA); }
        COMPUTE(t0 + 2, aB, h0);
        EMIT(t0 + 1);
        SHIFTH;
    }
}

// ---------------- softmax over D of -belief, expectation of d ----------------
__global__ void softmax_disp(const float* __restrict__ bel, float* __restrict__ disp) {
    int p = blockIdx.x * 256 + threadIdx.x;
    if (p >= HW) return;
    float v[ND];
    float m = -1e30f;
#pragma unroll
    for (int d = 0; d < ND; d++) {
        v[d] = -bel[d * HW + p];
        m = fmaxf(m, v[d]);
    }
    float s = 0.f, ws = 0.f;
#pragma unroll
    for (int d = 0; d < ND; d++) {
        float e = __expf(v[d] - m);
        s += e;
        ws += e * (float)d;
    }
    disp[p] = ws / s;
}

// ---------------- concat left_img(3ch) + disparity -> 4ch ----------------
__global__ void concat4(const float* __restrict__ left, const float* __restrict__ disp,
                        float* __restrict__ x4) {
    int idx = blockIdx.x * 256 + threadIdx.x;
    if (idx >= 4 * HW) return;
    int c = idx / HW, p = idx % HW;
    x4[idx] = (c < 3) ? left[idx] : disp[p];
}

extern "C" void kernel_launch(void* const* d_in, const int* in_sizes, int n_in,
                              void* d_out, int out_size, void* d_ws, size_t ws_size,
                              hipStream_t stream) {
    const float* left   = (const float*)d_in[0];
    const float* right  = (const float*)d_in[1];
    const float* fe_w1  = (const float*)d_in[2];
    const float* fe_b1  = (const float*)d_in[3];
    const float* fe_w2  = (const float*)d_in[4];
    const float* fe_b2  = (const float*)d_in[5];
    const float* cv_w   = (const float*)d_in[6];
    const float* cv_b   = (const float*)d_in[7];
    const float* mp_w1  = (const float*)d_in[8];
    const float* mp_b1  = (const float*)d_in[9];
    const float* mp_w2  = (const float*)d_in[10];
    const float* mp_b2  = (const float*)d_in[11];
    const float* rf_w1  = (const float*)d_in[12];
    const float* rf_b1  = (const float*)d_in[13];
    const float* rf_w2  = (const float*)d_in[14];
    const float* rf_b2  = (const float*)d_in[15];
    const float* rf_w3  = (const float*)d_in[16];
    const float* rf_b3  = (const float*)d_in[17];
    float* out = (float*)d_out;

    float* ws = (float*)d_ws;
    // layout (floats):
    float* At    = ws;                  // 2M floats [HW][64]; also fe tmp (1M) earlier, r1 later
    float* tmp   = ws;                  // fe intermediate (1M), before At exists
    float* lf    = ws + 2097152;        // 32*HW
    float* rfeat = ws + 3145728;        // 32*HW (r2 aliases later)
    float* cost  = ws + 4194304;        // 32*HW  (raw A transient before cost_expand)
    float* Araw  = ws + 4194304;        // 2M floats transient (= cost+bel regions)
    float* bel   = ws + 5242880;        // 32*HW
    float* bel2  = ws + 6291456;        // 32*HW
    float* lsum  = ws + 7340032;        // HW
    float* rsum  = ws + 7372800;        // HW
    float* disp  = ws + 7405568;        // HW
    float* x4    = ws + 7438336;        // 4*HW

    dim3 blk(256);
    dim3 gconv(8, 16, 4);   // COUT=32
    dim3 gconv64(8, 16, 8); // COUT=64
    dim3 gconv1(8, 16, 1);  // COUT=1

    // feature extraction
    conv3x3<<<gconv, blk, 0, stream>>>(left, tmp, fe_w1, fe_b1, 3, 32, 27, 1, nullptr);
    conv3x3<<<gconv, blk, 0, stream>>>(tmp, lf, fe_w2, fe_b2, 32, 32, 288, 1, nullptr);
    conv3x3<<<gconv, blk, 0, stream>>>(right, tmp, fe_w1, fe_b1, 3, 32, 27, 1, nullptr);
    conv3x3<<<gconv, blk, 0, stream>>>(tmp, rfeat, fe_w2, fe_b2, 32, 32, 288, 1, nullptr);

    // cost volume (separated)
    chan_dot<<<dim3(HW / 256), blk, 0, stream>>>(lf, rfeat, cv_w, lsum, rsum);

    // hoisted lf-part of mp conv1 (includes mp_b1, no relu) -> Araw, then transpose -> At
    conv3x3<<<gconv64, blk, 0, stream>>>(lf, Araw, mp_w1, mp_b1, 32, 64, 297, 0, nullptr);
    a_transpose<<<dim3(HW / 64), blk, 0, stream>>>(Araw, At);

    // cost + belief init (overwrites Araw region, after transpose in stream order)
    cost_expand<<<dim3(ND * HW / 256), blk, 0, stream>>>(lsum, rsum, cv_b, cost, bel);

    // 5 MP iterations, ping-pong — 1 wave per block, 4096 blocks
    dim3 gmp(4096);
    dim3 wblk(64);
    mp_iter_fast<<<gmp, wblk, 0, stream>>>(At, cost, bel,  bel2, mp_w1, mp_w2, mp_b2);
    mp_iter_fast<<<gmp, wblk, 0, stream>>>(At, cost, bel2, bel,  mp_w1, mp_w2, mp_b2);
    mp_iter_fast<<<gmp, wblk, 0, stream>>>(At, cost, bel,  bel2, mp_w1, mp_w2, mp_b2);
    mp_iter_fast<<<gmp, wblk, 0, stream>>>(At, cost, bel2, bel,  mp_w1, mp_w2, mp_b2);
    mp_iter_fast<<<gmp, wblk, 0, stream>>>(At, cost, bel,  bel2, mp_w1, mp_w2, mp_b2);

    softmax_disp<<<dim3(HW / 256), blk, 0, stream>>>(bel2, disp);

    // refinement (At dead now; reuse ws+0 for r1); final residual add fused into last conv
    concat4<<<dim3(4 * HW / 256), blk, 0, stream>>>(left, disp, x4);
    conv3x3<<<gconv, blk, 0, stream>>>(x4, At, rf_w1, rf_b1, 4, 32, 36, 1, nullptr);
    conv3x3<<<gconv, blk, 0, stream>>>(At, rfeat, rf_w2, rf_b2, 32, 32, 288, 1, nullptr);
    conv3x3<<<gconv1, blk, 0, stream>>>(rfeat, out, rf_w3, rf_b3, 32, 1, 288, 0, disp);
}

// Round 6
// 559.471 us; speedup vs baseline: 2.3328x; 1.2364x over previous
//
#include <hip/hip_runtime.h>
#include <hip/hip_bf16.h>

#define H 128
#define W 256
#define HW (H*W)
#define NC 32
#define ND 32
#define NHID 64

// ---- 3x3 same-pad conv v2: weights in LDS, double-buffered 4-cin stages, optional img pair ----
// grid: (W/32, H/8, nimg * ceil(COUT/8)), block 256 (32x8 px, 1 px/thread)
__global__ __launch_bounds__(256) void conv3x3(
        const float* __restrict__ in0, const float* __restrict__ in1,
        float* __restrict__ out0, float* __restrict__ out1,
        const float* __restrict__ w, const float* __restrict__ b,
        int CIN, int COUT, int wstride, int dorelu,
        const float* __restrict__ addin) {
    __shared__ float wS[2304];              // up to 8 couts x 32 cin x 9
    __shared__ float tile[2][4][10][35];    // double-buffered 4-cin halo tiles
    const int tid = threadIdx.x;
    const int zg = (COUT + 7) >> 3;
    const int img = blockIdx.z / zg;
    const int cog = blockIdx.z % zg;
    const float* in = img ? in1 : in0;
    float* out = img ? out1 : out0;
    const int cobase = cog * 8;
    int nco = COUT - cobase; if (nco > 8) nco = 8;
    const int gx0 = blockIdx.x * 32, gy0 = blockIdx.y * 8;
    const int tx = tid & 31, ty = tid >> 5;

    // stage weights for this block's couts (LDS broadcast reads later)
    const int wcnt = nco * CIN * 9;
    for (int i = tid; i < wcnt; i += 256) {
        int co = i / (CIN * 9), rem = i % (CIN * 9);
        wS[i] = w[(size_t)(cobase + co) * wstride + rem];
    }

    const int nst = (CIN + 3) >> 2;
    // stage 0
    {
        int nch = CIN < 4 ? CIN : 4;
        for (int i = tid; i < nch * 340; i += 256) {
            int ch = i / 340, rem = i % 340;
            int r = rem / 34, cc = rem % 34;
            int gy = gy0 + r - 1, gx = gx0 + cc - 1;
            tile[0][ch][r][cc] = (gy >= 0 && gy < H && gx >= 0 && gx < W)
                                 ? in[(size_t)ch * HW + gy * W + gx] : 0.f;
        }
    }
    __syncthreads();

    float acc[8];
#pragma unroll
    for (int i = 0; i < 8; i++) acc[i] = 0.f;

    for (int s = 0; s < nst; s++) {
        const int c0 = s * 4;
        int nch = CIN - c0; if (nch > 4) nch = 4;
        // prefetch next stage into other buffer (overlaps with compute below)
        if (s + 1 < nst) {
            const int c1 = c0 + 4;
            int nch2 = CIN - c1; if (nch2 > 4) nch2 = 4;
            const int nb = (s + 1) & 1;
            for (int i = tid; i < nch2 * 340; i += 256) {
                int ch = i / 340, rem = i % 340;
                int r = rem / 34, cc = rem % 34;
                int gy = gy0 + r - 1, gx = gx0 + cc - 1;
                tile[nb][ch][r][cc] = (gy >= 0 && gy < H && gx >= 0 && gx < W)
                                      ? in[(size_t)(c1 + ch) * HW + gy * W + gx] : 0.f;
            }
        }
        const int cb = s & 1;
        for (int ch = 0; ch < nch; ch++) {
            float v[9];
#pragma unroll
            for (int ky = 0; ky < 3; ky++)
#pragma unroll
                for (int kx = 0; kx < 3; kx++)
                    v[ky * 3 + kx] = tile[cb][ch][ty + ky][tx + kx];
            const int wb = (c0 + ch) * 9;
#pragma unroll
            for (int co = 0; co < 8; co++) {
                if (co < nco) {
                    const float* wp = &wS[co * CIN * 9 + wb];
#pragma unroll
                    for (int k = 0; k < 9; k++) acc[co] += wp[k] * v[k];
                }
            }
        }
        __syncthreads();
    }

    const int gy = gy0 + ty, gx = gx0 + tx;
    const float ad = addin ? addin[gy * W + gx] : 0.f;
#pragma unroll
    for (int co = 0; co < 8; co++) {
        if (co < nco) {
            float r = acc[co] + b[cobase + co];
            if (dorelu) r = fmaxf(r, 0.f);
            r += ad;
            out[(size_t)(cobase + co) * HW + gy * W + gx] = r;
        }
    }
}

// ---------------- per-pixel channel dot for cost volume separation ----------------
__global__ void chan_dot(const float* __restrict__ lf, const float* __restrict__ rf,
                         const float* __restrict__ cvw,
                         float* __restrict__ lsum, float* __restrict__ rsum) {
    int p = blockIdx.x * 256 + threadIdx.x;
    if (p >= HW) return;
    float ls = 0.f, rs = 0.f;
    for (int c = 0; c < NC; c++) {
        ls += lf[c * HW + p] * cvw[c];
        rs += rf[c * HW + p] * cvw[NC + c];
    }
    lsum[p] = ls;
    rsum[p] = rs;
}

// ---------------- cost[d,h,w] = lsum + shift(rsum, d) + cv_b; belief init ----------------
__global__ void cost_expand(const float* __restrict__ lsum, const float* __restrict__ rsum,
                            const float* __restrict__ cvb,
                            float* __restrict__ cost, float* __restrict__ bel) {
    int idx = blockIdx.x * 256 + threadIdx.x;
    if (idx >= ND * HW) return;
    int d = idx / HW, p = idx % HW;
    int col = p & (W - 1);
    float c = lsum[p] + cvb[0];
    if (col >= d) c += rsum[p - d];
    cost[idx] = c;
    bel[idx] = c;
}

// ---------------- A[hid][p] -> At[p][hid] (LDS tile transpose) ----------------
__global__ void a_transpose(const float* __restrict__ A, float* __restrict__ At) {
    __shared__ float t[64][65];
    int p0 = blockIdx.x * 64;
    int tx = threadIdx.x & 63;
    int ty = threadIdx.x >> 6;   // 0..3
#pragma unroll
    for (int r = 0; r < 16; r++) {
        int hid = ty * 16 + r;
        t[tx][hid] = A[(size_t)hid * HW + p0 + tx];
    }
    __syncthreads();
#pragma unroll
    for (int r = 0; r < 16; r++) {
        int p = ty * 16 + r;
        At[(size_t)(p0 + p) * 64 + tx] = t[p][tx];
    }
}

// ---------------- fast MP iteration v4: pipelined At rows + 3-way register rotation ----------------
#define LOADROW(YC, AR)                                                        \
  {                                                                            \
    if ((YC) >= 0 && (YC) < H) {                                               \
      AR[0] = bp[e0off];                                                       \
      _Pragma("unroll") for (int j = 1; j < 17; j++) AR[j] = bp[(j - 8) * 64]; \
      AR[17] = bp[e17off];                                                     \
    }                                                                          \
    bp += W * 64;                                                              \
  }

#define COMPUTE(U, AR, HARR)                                                   \
  {                                                                            \
    const int yc_ = y0 + (U);                                                  \
    if (yc_ < 0 || yc_ >= H) {                                                 \
      _Pragma("unroll") for (int j = 0; j < 18; j++) HARR[j] = 0.f;            \
    } else {                                                                   \
      float bw_[3][3];                                                         \
      _Pragma("unroll") for (int r = 0; r < 3; r++) {                          \
        bw_[r][0] = belS[(U) + 1 + r][0];                                      \
        bw_[r][1] = belS[(U) + 1 + r][1];                                      \
      }                                                                        \
      _Pragma("unroll") for (int j = 0; j < 18; j++) {                         \
        float acc_ = AR[j];                                                    \
        _Pragma("unroll") for (int r = 0; r < 3; r++)                          \
          bw_[r][(j + 2) % 3] = belS[(U) + 1 + r][j + 2];                      \
        _Pragma("unroll") for (int r = 0; r < 3; r++)                          \
          _Pragma("unroll") for (int c = 0; c < 3; c++)                        \
            acc_ += w1[r * 3 + c] * bw_[r][(j + c) % 3];                       \
        HARR[j] = fmaxf(acc_, 0.f);                                            \
      }                                                                        \
      if (x0 == 0) HARR[0] = 0.f;                                              \
      if (x0 == W - 16) HARR[17] = 0.f;                                        \
    }                                                                          \
  }

#define EMIT3(T, HH2, HH1, HH0)                                                \
  {                                                                            \
    _Pragma("unroll") for (int jo = 0; jo < 16; jo++) {                        \
      float pp = w2[0] * HH2[jo] + w2[1] * HH2[jo + 1] + w2[2] * HH2[jo + 2]   \
               + w2[3] * HH1[jo] + w2[4] * HH1[jo + 1] + w2[5] * HH1[jo + 2]   \
               + w2[6] * HH0[jo] + w2[7] * HH0[jo + 1] + w2[8] * HH0[jo + 2];  \
      partS[jo][lane] = pp;                                                    \
    }                                                                          \
    asm volatile("s_waitcnt lgkmcnt(0)" ::: "memory");                         \
    {                                                                          \
      const float4* pr = (const float4*)&partS[pq][qq * 16];                   \
      float4 v0 = pr[0], v1 = pr[1], v2 = pr[2], v3 = pr[3];                   \
      float s_ = (((v0.x + v0.y) + (v0.z + v0.w)) +                            \
                  ((v1.x + v1.y) + (v1.z + v1.w))) +                           \
                 (((v2.x + v2.y) + (v2.z + v2.w)) +                            \
                  ((v3.x + v3.y) + (v3.z + v3.w)));                            \
      s_ += __shfl_xor(s_, 16);                                                \
      s_ += __shfl_xor(s_, 32);                                                \
      if (qq == 0)                                                             \
        bout[obase + (size_t)(T) * W] = costS[(T)][pq] + s_ + b2;              \
      asm volatile("s_waitcnt lgkmcnt(0)" ::: "memory");                       \
    }                                                                          \
  }

// one output row: load row T+2 into AOUT, compute hdn(T+1) into H0, emit row T
#define STEP(T, AIN, AOUT, HX2, HX1, HX0, DOLOAD)                              \
  {                                                                            \
    if (DOLOAD) { LOADROW(y0 + (T) + 2, AOUT); }                               \
    COMPUTE((T) + 1, AIN, HX0);                                                \
    EMIT3(T, HX2, HX1, HX0);                                                   \
  }

__global__ __launch_bounds__(64, 1) void mp_iter_fast(
    const float* __restrict__ At,    // [HW][64]
    const float* __restrict__ cost,
    const float* __restrict__ bin,
    float* __restrict__ bout,
    const float* __restrict__ mp_w1,
    const float* __restrict__ mp_w2,
    const float* __restrict__ mp_b2) {
    __shared__ float belS[20][20];
    __shared__ float costS[16][16];
    __shared__ float partS[16][68];

    const int lane = threadIdx.x;    // = hid
    const int i = blockIdx.x;
    const int xcd = i & 7;
    const int jj = i >> 3;
    const int sl = jj & 15;
    const int d = jj >> 4;
    const int strip = xcd * 16 + sl;
    const int x0 = (strip & 15) * 16;
    const int y0 = (strip >> 4) * 16;

    float w1[9], w2[9];
#pragma unroll
    for (int k = 0; k < 9; k++) {
        w1[k] = mp_w1[lane * 297 + 288 + k];
        w2[k] = mp_w2[lane * 9 + k];
    }
    const float b2 = mp_b2[0];

    const float* bp = At + (size_t)(y0 - 1) * (W * 64) + (x0 + 7) * 64 + lane;
    const int e0off  = (x0 == 0)      ? -448 : -512;
    const int e17off = (x0 == W - 16) ?  512 :  576;

    const float* beld = bin + (size_t)d * HW;
#pragma unroll
    for (int it = 0; it < 7; it++) {
        int idx = it * 64 + lane;
        if (idx < 400) {
            int r = idx / 20, c = idx % 20;
            int gy = y0 - 2 + r, gx = x0 - 2 + c;
            belS[r][c] = (gy >= 0 && gy < H && gx >= 0 && gx < W) ? beld[gy * W + gx] : 0.f;
        }
    }
#pragma unroll
    for (int it = 0; it < 4; it++) {
        int idx = it * 64 + lane;
        int r = idx >> 4, c = idx & 15;
        costS[r][c] = cost[(size_t)d * HW + (size_t)(y0 + r) * W + x0 + c];
    }
    __syncthreads();

    const int pq = lane & 15, qq = lane >> 4;
    const size_t obase = (size_t)d * HW + (size_t)y0 * W + x0 + pq;

    float aA[18], aB[18];
    float hA[18], hB[18], hC[18];

    LOADROW(y0 - 1, aA);
    LOADROW(y0, aB);
    COMPUTE(-1, aA, hA);
    LOADROW(y0 + 1, aA);
    COMPUTE(0, aB, hB);

    STEP(0,  aA, aB, hA, hB, hC, 1)
    STEP(1,  aB, aA, hB, hC, hA, 1)
    STEP(2,  aA, aB, hC, hA, hB, 1)
    STEP(3,  aB, aA, hA, hB, hC, 1)
    STEP(4,  aA, aB, hB, hC, hA, 1)
    STEP(5,  aB, aA, hC, hA, hB, 1)
    STEP(6,  aA, aB, hA, hB, hC, 1)
    STEP(7,  aB, aA, hB, hC, hA, 1)
    STEP(8,  aA, aB, hC, hA, hB, 1)
    STEP(9,  aB, aA, hA, hB, hC, 1)
    STEP(10, aA, aB, hB, hC, hA, 1)
    STEP(11, aB, aA, hC, hA, hB, 1)
    STEP(12, aA, aB, hA, hB, hC, 1)
    STEP(13, aB, aA, hB, hC, hA, 1)
    STEP(14, aA, aB, hC, hA, hB, 1)
    STEP(15, aB, aA, hA, hB, hC, 0)
}

// ---------------- softmax over D of -belief + disparity + x4 concat fused ----------------
__global__ void softmax_disp(const float* __restrict__ bel, const float* __restrict__ left,
                             float* __restrict__ disp, float* __restrict__ x4) {
    int p = blockIdx.x * 256 + threadIdx.x;
    if (p >= HW) return;
    float v[ND];
    float m = -1e30f;
#pragma unroll
    for (int d = 0; d < ND; d++) {
        v[d] = -bel[d * HW + p];
        m = fmaxf(m, v[d]);
    }
    float s = 0.f, ws = 0.f;
#pragma unroll
    for (int d = 0; d < ND; d++) {
        float e = __expf(v[d] - m);
        s += e;
        ws += e * (float)d;
    }
    float dv = ws / s;
    disp[p] = dv;
    x4[3 * HW + p] = dv;
    x4[p] = left[p];
    x4[HW + p] = left[HW + p];
    x4[2 * HW + p] = left[2 * HW + p];
}

extern "C" void kernel_launch(void* const* d_in, const int* in_sizes, int n_in,
                              void* d_out, int out_size, void* d_ws, size_t ws_size,
                              hipStream_t stream) {
    const float* left   = (const float*)d_in[0];
    const float* right  = (const float*)d_in[1];
    const float* fe_w1  = (const float*)d_in[2];
    const float* fe_b1  = (const float*)d_in[3];
    const float* fe_w2  = (const float*)d_in[4];
    const float* fe_b2  = (const float*)d_in[5];
    const float* cv_w   = (const float*)d_in[6];
    const float* cv_b   = (const float*)d_in[7];
    const float* mp_w1  = (const float*)d_in[8];
    const float* mp_b1  = (const float*)d_in[9];
    const float* mp_w2  = (const float*)d_in[10];
    const float* mp_b2  = (const float*)d_in[11];
    const float* rf_w1  = (const float*)d_in[12];
    const float* rf_b1  = (const float*)d_in[13];
    const float* rf_w2  = (const float*)d_in[14];
    const float* rf_b2  = (const float*)d_in[15];
    const float* rf_w3  = (const float*)d_in[16];
    const float* rf_b3  = (const float*)d_in[17];
    float* out = (float*)d_out;

    float* ws = (float*)d_ws;
    // layout (floats):
    float* At    = ws;                  // 2M floats [HW][64]; also {tmp0,tmp1} earlier, r1 later
    float* tmp0  = ws;                  // fe intermediate left (1M region half)
    float* tmp1  = ws + 1048576;        // fe intermediate right
    float* lf    = ws + 2097152;        // 32*HW
    float* rfeat = ws + 3145728;        // 32*HW (r2 aliases later)
    float* cost  = ws + 4194304;        // 32*HW  (Araw transient before cost_expand)
    float* Araw  = ws + 4194304;        // 2M floats transient (= cost+bel regions)
    float* bel   = ws + 5242880;        // 32*HW
    float* bel2  = ws + 6291456;        // 32*HW
    float* lsum  = ws + 7340032;        // HW
    float* rsum  = ws + 7372800;        // HW
    float* disp  = ws + 7405568;        // HW
    float* x4    = ws + 7438336;        // 4*HW

    dim3 blk(256);

    // feature extraction: left+right fused via z
    conv3x3<<<dim3(8, 16, 8), blk, 0, stream>>>(left, right, tmp0, tmp1, fe_w1, fe_b1, 3, 32, 27, 1, nullptr);
    conv3x3<<<dim3(8, 16, 8), blk, 0, stream>>>(tmp0, tmp1, lf, rfeat, fe_w2, fe_b2, 32, 32, 288, 1, nullptr);

    // cost volume (separated)
    chan_dot<<<dim3(HW / 256), blk, 0, stream>>>(lf, rfeat, cv_w, lsum, rsum);

    // hoisted lf-part of mp conv1 (includes mp_b1, no relu) -> Araw, then transpose -> At
    conv3x3<<<dim3(8, 16, 8), blk, 0, stream>>>(lf, lf, Araw, Araw, mp_w1, mp_b1, 32, 64, 297, 0, nullptr);
    a_transpose<<<dim3(HW / 64), blk, 0, stream>>>(Araw, At);

    // cost + belief init (overwrites Araw region, after transpose in stream order)
    cost_expand<<<dim3(ND * HW / 256), blk, 0, stream>>>(lsum, rsum, cv_b, cost, bel);

    // 5 MP iterations, ping-pong — 1 wave per block, 4096 blocks
    dim3 gmp(4096);
    dim3 wblk(64);
    mp_iter_fast<<<gmp, wblk, 0, stream>>>(At, cost, bel,  bel2, mp_w1, mp_w2, mp_b2);
    mp_iter_fast<<<gmp, wblk, 0, stream>>>(At, cost, bel2, bel,  mp_w1, mp_w2, mp_b2);
    mp_iter_fast<<<gmp, wblk, 0, stream>>>(At, cost, bel,  bel2, mp_w1, mp_w2, mp_b2);
    mp_iter_fast<<<gmp, wblk, 0, stream>>>(At, cost, bel2, bel,  mp_w1, mp_w2, mp_b2);
    mp_iter_fast<<<gmp, wblk, 0, stream>>>(At, cost, bel,  bel2, mp_w1, mp_w2, mp_b2);

    // softmax + disparity + x4 concat
    softmax_disp<<<dim3(HW / 256), blk, 0, stream>>>(bel2, left, disp, x4);

    // refinement (At dead now; reuse ws+0 for r1); final residual add fused into last conv
    conv3x3<<<dim3(8, 16, 4), blk, 0, stream>>>(x4, x4, At, At, rf_w1, rf_b1, 4, 32, 36, 1, nullptr);
    conv3x3<<<dim3(8, 16, 4), blk, 0, stream>>>(At, At, rfeat, rfeat, rf_w2, rf_b2, 32, 32, 288, 1, nullptr);
    conv3x3<<<dim3(8, 16, 1), blk, 0, stream>>>(rfeat, rfeat, out, out, rf_w3, rf_b3, 32, 1, 288, 0, disp);
}

// Round 7
// 553.529 us; speedup vs baseline: 2.3579x; 1.0107x over previous
//
#include <hip/hip_runtime.h>
#include <hip/hip_bf16.h>

#define H 128
#define W 256
#define HW (H*W)
#define NC 32
#define ND 32
#define NHID 64

// ---- 3x3 same-pad conv v2: weights in LDS, double-buffered 4-cin stages, optional img pair ----
__global__ __launch_bounds__(256) void conv3x3(
        const float* __restrict__ in0, const float* __restrict__ in1,
        float* __restrict__ out0, float* __restrict__ out1,
        const float* __restrict__ w, const float* __restrict__ b,
        int CIN, int COUT, int wstride, int dorelu,
        const float* __restrict__ addin) {
    __shared__ float wS[2304];
    __shared__ float tile[2][4][10][35];
    const int tid = threadIdx.x;
    const int zg = (COUT + 7) >> 3;
    const int img = blockIdx.z / zg;
    const int cog = blockIdx.z % zg;
    const float* in = img ? in1 : in0;
    float* out = img ? out1 : out0;
    const int cobase = cog * 8;
    int nco = COUT - cobase; if (nco > 8) nco = 8;
    const int gx0 = blockIdx.x * 32, gy0 = blockIdx.y * 8;
    const int tx = tid & 31, ty = tid >> 5;

    const int wcnt = nco * CIN * 9;
    for (int i = tid; i < wcnt; i += 256) {
        int co = i / (CIN * 9), rem = i % (CIN * 9);
        wS[i] = w[(size_t)(cobase + co) * wstride + rem];
    }

    const int nst = (CIN + 3) >> 2;
    {
        int nch = CIN < 4 ? CIN : 4;
        for (int i = tid; i < nch * 340; i += 256) {
            int ch = i / 340, rem = i % 340;
            int r = rem / 34, cc = rem % 34;
            int gy = gy0 + r - 1, gx = gx0 + cc - 1;
            tile[0][ch][r][cc] = (gy >= 0 && gy < H && gx >= 0 && gx < W)
                                 ? in[(size_t)ch * HW + gy * W + gx] : 0.f;
        }
    }
    __syncthreads();

    float acc[8];
#pragma unroll
    for (int i = 0; i < 8; i++) acc[i] = 0.f;

    for (int s = 0; s < nst; s++) {
        const int c0 = s * 4;
        int nch = CIN - c0; if (nch > 4) nch = 4;
        if (s + 1 < nst) {
            const int c1 = c0 + 4;
            int nch2 = CIN - c1; if (nch2 > 4) nch2 = 4;
            const int nb = (s + 1) & 1;
            for (int i = tid; i < nch2 * 340; i += 256) {
                int ch = i / 340, rem = i % 340;
                int r = rem / 34, cc = rem % 34;
                int gy = gy0 + r - 1, gx = gx0 + cc - 1;
                tile[nb][ch][r][cc] = (gy >= 0 && gy < H && gx >= 0 && gx < W)
                                      ? in[(size_t)(c1 + ch) * HW + gy * W + gx] : 0.f;
            }
        }
        const int cb = s & 1;
        for (int ch = 0; ch < nch; ch++) {
            float v[9];
#pragma unroll
            for (int ky = 0; ky < 3; ky++)
#pragma unroll
                for (int kx = 0; kx < 3; kx++)
                    v[ky * 3 + kx] = tile[cb][ch][ty + ky][tx + kx];
            const int wb = (c0 + ch) * 9;
#pragma unroll
            for (int co = 0; co < 8; co++) {
                if (co < nco) {
                    const float* wp = &wS[co * CIN * 9 + wb];
#pragma unroll
                    for (int k = 0; k < 9; k++) acc[co] += wp[k] * v[k];
                }
            }
        }
        __syncthreads();
    }

    const int gy = gy0 + ty, gx = gx0 + tx;
    const float ad = addin ? addin[gy * W + gx] : 0.f;
#pragma unroll
    for (int co = 0; co < 8; co++) {
        if (co < nco) {
            float r = acc[co] + b[cobase + co];
            if (dorelu) r = fmaxf(r, 0.f);
            r += ad;
            out[(size_t)(cobase + co) * HW + gy * W + gx] = r;
        }
    }
}

// ---------------- per-pixel channel dot for cost volume separation ----------------
__global__ void chan_dot(const float* __restrict__ lf, const float* __restrict__ rf,
                         const float* __restrict__ cvw,
                         float* __restrict__ lsum, float* __restrict__ rsum) {
    int p = blockIdx.x * 256 + threadIdx.x;
    if (p >= HW) return;
    float ls = 0.f, rs = 0.f;
    for (int c = 0; c < NC; c++) {
        ls += lf[c * HW + p] * cvw[c];
        rs += rf[c * HW + p] * cvw[NC + c];
    }
    lsum[p] = ls;
    rsum[p] = rs;
}

// ---------------- cost[d,h,w] = lsum + shift(rsum, d) + cv_b; belief init ----------------
__global__ void cost_expand(const float* __restrict__ lsum, const float* __restrict__ rsum,
                            const float* __restrict__ cvb,
                            float* __restrict__ cost, float* __restrict__ bel) {
    int idx = blockIdx.x * 256 + threadIdx.x;
    if (idx >= ND * HW) return;
    int d = idx / HW, p = idx % HW;
    int col = p & (W - 1);
    float c = lsum[p] + cvb[0];
    if (col >= d) c += rsum[p - d];
    cost[idx] = c;
    bel[idx] = c;
}

// ---------------- A[hid][p] -> At[p][hid] (LDS tile transpose) ----------------
__global__ void a_transpose(const float* __restrict__ A, float* __restrict__ At) {
    __shared__ float t[64][65];
    int p0 = blockIdx.x * 64;
    int tx = threadIdx.x & 63;
    int ty = threadIdx.x >> 6;
#pragma unroll
    for (int r = 0; r < 16; r++) {
        int hid = ty * 16 + r;
        t[tx][hid] = A[(size_t)hid * HW + p0 + tx];
    }
    __syncthreads();
#pragma unroll
    for (int r = 0; r < 16; r++) {
        int p = ty * 16 + r;
        At[(size_t)(p0 + p) * 64 + tx] = t[p][tx];
    }
}

// ---- MP iteration v5: 4 INDEPENDENT waves per 256-block, zero __syncthreads ----
// Each wave owns (d, strip) with private LDS slice; wave-local lgkmcnt ordering only.
#define LOADROW(YC, AR)                                                        \
  {                                                                            \
    if ((YC) >= 0 && (YC) < H) {                                               \
      AR[0] = bp[e0off];                                                       \
      _Pragma("unroll") for (int j = 1; j < 17; j++) AR[j] = bp[(j - 8) * 64]; \
      AR[17] = bp[e17off];                                                     \
    }                                                                          \
    bp += W * 64;                                                              \
  }

#define COMPUTE(U, AR, HARR)                                                   \
  {                                                                            \
    const int yc_ = y0 + (U);                                                  \
    if (yc_ < 0 || yc_ >= H) {                                                 \
      _Pragma("unroll") for (int j = 0; j < 18; j++) HARR[j] = 0.f;            \
    } else {                                                                   \
      float bw_[3][3];                                                         \
      _Pragma("unroll") for (int r = 0; r < 3; r++) {                          \
        bw_[r][0] = belW[(U) + 1 + r][0];                                      \
        bw_[r][1] = belW[(U) + 1 + r][1];                                      \
      }                                                                        \
      _Pragma("unroll") for (int j = 0; j < 18; j++) {                         \
        float acc_ = AR[j];                                                    \
        _Pragma("unroll") for (int r = 0; r < 3; r++)                          \
          bw_[r][(j + 2) % 3] = belW[(U) + 1 + r][j + 2];                      \
        _Pragma("unroll") for (int r = 0; r < 3; r++)                          \
          _Pragma("unroll") for (int c = 0; c < 3; c++)                        \
            acc_ += w1[r * 3 + c] * bw_[r][(j + c) % 3];                       \
        HARR[j] = fmaxf(acc_, 0.f);                                            \
      }                                                                        \
      if (x0 == 0) HARR[0] = 0.f;                                              \
      if (x0 == W - 16) HARR[17] = 0.f;                                        \
    }                                                                          \
  }

#define EMIT3(T, HH2, HH1, HH0)                                                \
  {                                                                            \
    _Pragma("unroll") for (int jo = 0; jo < 16; jo++) {                        \
      float pp = w2[0] * HH2[jo] + w2[1] * HH2[jo + 1] + w2[2] * HH2[jo + 2]   \
               + w2[3] * HH1[jo] + w2[4] * HH1[jo + 1] + w2[5] * HH1[jo + 2]   \
               + w2[6] * HH0[jo] + w2[7] * HH0[jo + 1] + w2[8] * HH0[jo + 2];  \
      partW[jo][lane] = pp;                                                    \
    }                                                                          \
    asm volatile("s_waitcnt lgkmcnt(0)" ::: "memory");                         \
    {                                                                          \
      const float4* pr = (const float4*)&partW[pq][qq * 16];                   \
      float4 v0 = pr[0], v1 = pr[1], v2 = pr[2], v3 = pr[3];                   \
      float s_ = (((v0.x + v0.y) + (v0.z + v0.w)) +                            \
                  ((v1.x + v1.y) + (v1.z + v1.w))) +                           \
                 (((v2.x + v2.y) + (v2.z + v2.w)) +                            \
                  ((v3.x + v3.y) + (v3.z + v3.w)));                            \
      s_ += __shfl_xor(s_, 16);                                                \
      s_ += __shfl_xor(s_, 32);                                                \
      if (qq == 0)                                                             \
        bout[obase + (size_t)(T) * W] = costW[(T)][pq] + s_ + b2;              \
      asm volatile("s_waitcnt lgkmcnt(0)" ::: "memory");                       \
    }                                                                          \
  }

#define STEP(T, AIN, AOUT, HX2, HX1, HX0, DOLOAD)                              \
  {                                                                            \
    if (DOLOAD) { LOADROW(y0 + (T) + 2, AOUT); }                               \
    COMPUTE((T) + 1, AIN, HX0);                                                \
    EMIT3(T, HX2, HX1, HX0);                                                   \
  }

__global__ __launch_bounds__(256, 1) void mp_iter_fast(
    const float* __restrict__ At,    // [HW][64]
    const float* __restrict__ cost,
    const float* __restrict__ bin,
    float* __restrict__ bout,
    const float* __restrict__ mp_w1,
    const float* __restrict__ mp_w2,
    const float* __restrict__ mp_b2) {
    __shared__ float belS[4][20][20];
    __shared__ float costS[4][16][16];
    __shared__ float partS[4][16][68];

    const int tid = threadIdx.x;
    const int lane = tid & 63;       // = hid
    const int lw = tid >> 6;         // independent wave in block
    float (*belW)[20]  = belS[lw];
    float (*costW)[16] = costS[lw];
    float (*partW)[68] = partS[lw];

    // XCD swizzle: XCD k owns y-band k (rows 16k..16k+15) across all x, all d.
    // Block's 4 waves = 4 consecutive d of the SAME strip -> share At rows in L1.
    const int i = blockIdx.x;
    const int xcd = i & 7;
    const int jj = i >> 3;           // 0..127
    const int sl = jj & 15;
    const int d4 = jj >> 4;          // 0..7
    const int strip = xcd * 16 + sl; // 0..127
    const int d = d4 * 4 + lw;       // 0..31
    const int x0 = (strip & 15) * 16;
    const int y0 = (strip >> 4) * 16;

    float w1[9], w2[9];
#pragma unroll
    for (int k = 0; k < 9; k++) {
        w1[k] = mp_w1[lane * 297 + 288 + k];
        w2[k] = mp_w2[lane * 9 + k];
    }
    const float b2 = mp_b2[0];

    const float* bp = At + (size_t)(y0 - 1) * (W * 64) + (x0 + 7) * 64 + lane;
    const int e0off  = (x0 == 0)      ? -448 : -512;
    const int e17off = (x0 == W - 16) ?  512 :  576;

    // wave-private staging (same wave stages and consumes -> lgkmcnt is enough)
    const float* beld = bin + (size_t)d * HW;
#pragma unroll
    for (int it = 0; it < 7; it++) {
        int idx = it * 64 + lane;
        if (idx < 400) {
            int r = idx / 20, c = idx % 20;
            int gy = y0 - 2 + r, gx = x0 - 2 + c;
            belW[r][c] = (gy >= 0 && gy < H && gx >= 0 && gx < W) ? beld[gy * W + gx] : 0.f;
        }
    }
#pragma unroll
    for (int it = 0; it < 4; it++) {
        int idx = it * 64 + lane;
        int r = idx >> 4, c = idx & 15;
        costW[r][c] = cost[(size_t)d * HW + (size_t)(y0 + r) * W + x0 + c];
    }
    asm volatile("s_waitcnt lgkmcnt(0)" ::: "memory");

    const int pq = lane & 15, qq = lane >> 4;
    const size_t obase = (size_t)d * HW + (size_t)y0 * W + x0 + pq;

    float aA[18], aB[18];
    float hA[18], hB[18], hC[18];

    LOADROW(y0 - 1, aA);
    LOADROW(y0, aB);
    COMPUTE(-1, aA, hA);
    LOADROW(y0 + 1, aA);
    COMPUTE(0, aB, hB);

    STEP(0,  aA, aB, hA, hB, hC, 1)
    STEP(1,  aB, aA, hB, hC, hA, 1)
    STEP(2,  aA, aB, hC, hA, hB, 1)
    STEP(3,  aB, aA, hA, hB, hC, 1)
    STEP(4,  aA, aB, hB, hC, hA, 1)
    STEP(5,  aB, aA, hC, hA, hB, 1)
    STEP(6,  aA, aB, hA, hB, hC, 1)
    STEP(7,  aB, aA, hB, hC, hA, 1)
    STEP(8,  aA, aB, hC, hA, hB, 1)
    STEP(9,  aB, aA, hA, hB, hC, 1)
    STEP(10, aA, aB, hB, hC, hA, 1)
    STEP(11, aB, aA, hC, hA, hB, 1)
    STEP(12, aA, aB, hA, hB, hC, 1)
    STEP(13, aB, aA, hB, hC, hA, 1)
    STEP(14, aA, aB, hC, hA, hB, 1)
    STEP(15, aB, aA, hA, hB, hC, 0)
}

// ---------------- softmax over D of -belief + disparity + x4 concat fused ----------------
__global__ void softmax_disp(const float* __restrict__ bel, const float* __restrict__ left,
                             float* __restrict__ disp, float* __restrict__ x4) {
    int p = blockIdx.x * 256 + threadIdx.x;
    if (p >= HW) return;
    float v[ND];
    float m = -1e30f;
#pragma unroll
    for (int d = 0; d < ND; d++) {
        v[d] = -bel[d * HW + p];
        m = fmaxf(m, v[d]);
    }
    float s = 0.f, ws = 0.f;
#pragma unroll
    for (int d = 0; d < ND; d++) {
        float e = __expf(v[d] - m);
        s += e;
        ws += e * (float)d;
    }
    float dv = ws / s;
    disp[p] = dv;
    x4[3 * HW + p] = dv;
    x4[p] = left[p];
    x4[HW + p] = left[HW + p];
    x4[2 * HW + p] = left[2 * HW + p];
}

extern "C" void kernel_launch(void* const* d_in, const int* in_sizes, int n_in,
                              void* d_out, int out_size, void* d_ws, size_t ws_size,
                              hipStream_t stream) {
    const float* left   = (const float*)d_in[0];
    const float* right  = (const float*)d_in[1];
    const float* fe_w1  = (const float*)d_in[2];
    const float* fe_b1  = (const float*)d_in[3];
    const float* fe_w2  = (const float*)d_in[4];
    const float* fe_b2  = (const float*)d_in[5];
    const float* cv_w   = (const float*)d_in[6];
    const float* cv_b   = (const float*)d_in[7];
    const float* mp_w1  = (const float*)d_in[8];
    const float* mp_b1  = (const float*)d_in[9];
    const float* mp_w2  = (const float*)d_in[10];
    const float* mp_b2  = (const float*)d_in[11];
    const float* rf_w1  = (const float*)d_in[12];
    const float* rf_b1  = (const float*)d_in[13];
    const float* rf_w2  = (const float*)d_in[14];
    const float* rf_b2  = (const float*)d_in[15];
    const float* rf_w3  = (const float*)d_in[16];
    const float* rf_b3  = (const float*)d_in[17];
    float* out = (float*)d_out;

    float* ws = (float*)d_ws;
    float* At    = ws;
    float* tmp0  = ws;
    float* tmp1  = ws + 1048576;
    float* lf    = ws + 2097152;
    float* rfeat = ws + 3145728;
    float* cost  = ws + 4194304;
    float* Araw  = ws + 4194304;
    float* bel   = ws + 5242880;
    float* bel2  = ws + 6291456;
    float* lsum  = ws + 7340032;
    float* rsum  = ws + 7372800;
    float* disp  = ws + 7405568;
    float* x4    = ws + 7438336;

    dim3 blk(256);

    conv3x3<<<dim3(8, 16, 8), blk, 0, stream>>>(left, right, tmp0, tmp1, fe_w1, fe_b1, 3, 32, 27, 1, nullptr);
    conv3x3<<<dim3(8, 16, 8), blk, 0, stream>>>(tmp0, tmp1, lf, rfeat, fe_w2, fe_b2, 32, 32, 288, 1, nullptr);

    chan_dot<<<dim3(HW / 256), blk, 0, stream>>>(lf, rfeat, cv_w, lsum, rsum);

    conv3x3<<<dim3(8, 16, 8), blk, 0, stream>>>(lf, lf, Araw, Araw, mp_w1, mp_b1, 32, 64, 297, 0, nullptr);
    a_transpose<<<dim3(HW / 64), blk, 0, stream>>>(Araw, At);

    cost_expand<<<dim3(ND * HW / 256), blk, 0, stream>>>(lsum, rsum, cv_b, cost, bel);

    // 5 MP iterations — 1024 blocks x 256 threads (4 independent waves/block)
    dim3 gmp(1024);
    mp_iter_fast<<<gmp, blk, 0, stream>>>(At, cost, bel,  bel2, mp_w1, mp_w2, mp_b2);
    mp_iter_fast<<<gmp, blk, 0, stream>>>(At, cost, bel2, bel,  mp_w1, mp_w2, mp_b2);
    mp_iter_fast<<<gmp, blk, 0, stream>>>(At, cost, bel,  bel2, mp_w1, mp_w2, mp_b2);
    mp_iter_fast<<<gmp, blk, 0, stream>>>(At, cost, bel2, bel,  mp_w1, mp_w2, mp_b2);
    mp_iter_fast<<<gmp, blk, 0, stream>>>(At, cost, bel,  bel2, mp_w1, mp_w2, mp_b2);

    softmax_disp<<<dim3(HW / 256), blk, 0, stream>>>(bel2, left, disp, x4);

    conv3x3<<<dim3(8, 16, 4), blk, 0, stream>>>(x4, x4, At, At, rf_w1, rf_b1, 4, 32, 36, 1, nullptr);
    conv3x3<<<dim3(8, 16, 4), blk, 0, stream>>>(At, At, rfeat, rfeat, rf_w2, rf_b2, 32, 32, 288, 1, nullptr);
    conv3x3<<<dim3(8, 16, 1), blk, 0, stream>>>(rfeat, rfeat, out, out, rf_w3, rf_b3, 32, 1, 288, 0, disp);
}